// Round 14
// baseline (658.232 us; speedup 1.0000x reference)
//
#include <hip/hip_runtime.h>
#include <cstdint>
#include <cstddef>

#define D 2048
#define L 8
#define KS 2048            // state/B k-extent (signed state)
#define BM 256
#define BN 128
#define BK 64
#define NT (KS / BK)       // 32 K-tiles
#define AROWS 256          // staged A rows
#define BUFSZ ((AROWS + 256) * BK)   // 32768 f16 = 64 KiB per buffer

typedef _Float16 f16;
typedef _Float16 f16x4 __attribute__((ext_vector_type(4)));
typedef _Float16 f16x8 __attribute__((ext_vector_type(8)));
typedef float f32x4 __attribute__((ext_vector_type(4)));
typedef float f32x16 __attribute__((ext_vector_type(16)));
typedef unsigned int u32x4 __attribute__((ext_vector_type(4)));

__device__ __forceinline__ void gload16(const void* g, void* l) {
  __builtin_amdgcn_global_load_lds(
      (const __attribute__((address_space(1))) void*)g,
      (__attribute__((address_space(3))) void*)l, 16, 0, 0);
}

// ---- init: signed A into both chains, bias init + step-0 contribution ------
__global__ __launch_bounds__(256) void k_init(
    const float* __restrict__ A, const float* __restrict__ b,
    const float* __restrict__ db1, const float* __restrict__ db2,  // layer 7
    f16* __restrict__ Ab, float* __restrict__ blbu, float* __restrict__ outacc) {
  const int m = blockIdx.x, tid = threadIdx.x;
  if (m < 2) {
    f32x4 z = {0.f, 0.f, 0.f, 0.f};
    *(f32x4*)(outacc + m * 2048 + tid * 8) = z;
    *(f32x4*)(outacc + m * 2048 + tid * 8 + 4) = z;
  }
  const int k = tid * 8;
  size_t i = (size_t)m * D + k;
  f32x4 a0 = *(const f32x4*)(A + i);
  f32x4 a1 = *(const f32x4*)(A + i + 4);
  f16x8 h;
  float cL = 0.f, cU = 0.f;
#pragma unroll
  for (int j = 0; j < 8; ++j) {
    float v = (j < 4) ? a0[j] : a1[j - 4];
    h[j] = (f16)v;
    float pf = fmaxf(v, 0.f), nf = fminf(v, 0.f);
    float w1 = db1[k + j], w2 = db2[k + j];
    cL += pf * w1 + nf * w2;
    cU += pf * w2 + nf * w1;
  }
  *(f16x8*)(Ab + (size_t)m * KS + k) = h;
  *(f16x8*)(Ab + (size_t)(D + m) * KS + k) = h;

  __shared__ float redL[4], redU[4];
#pragma unroll
  for (int off = 32; off > 0; off >>= 1) {
    cL += __shfl_down(cL, off);
    cU += __shfl_down(cU, off);
  }
  const int wave = tid >> 6, lane = tid & 63;
  if (lane == 0) { redL[wave] = cL; redU[wave] = cU; }
  __syncthreads();
  if (tid == 0) {
    float bL = b[m] + redL[0] + redL[1] + redL[2] + redL[3];
    float bU = b[m] + redU[0] + redU[1] + redU[2] + redU[3];
    blbu[m] = bL; blbu[D + m] = bU;
  }
}

// ---- standalone prep: Bsum/Bdif transposed panels (layer 7 bootstrap) ------
__global__ __launch_bounds__(512) void k_prep(
    const float* __restrict__ srcAl, const float* __restrict__ srcAu,
    f16* __restrict__ Bb) {
  const int p = blockIdx.x, tid = threadIdx.x;
  const size_t MS = (size_t)D * D;
  const int col = (p & 31) * 64 + (tid & 63);
  const int k0 = (p >> 5) * 64 + (tid >> 6) * 8;
  float sl[8], su[8];
#pragma unroll
  for (int j = 0; j < 8; ++j) {
    sl[j] = srcAl[(size_t)(k0 + j) * D + col];
    su[j] = srcAu[(size_t)(k0 + j) * D + col];
  }
  f16x8 hs, hd;
#pragma unroll
  for (int j = 0; j < 8; ++j) {
    hs[j] = (f16)((sl[j] + su[j]) * 0.5f);
    hd[j] = (f16)((sl[j] - su[j]) * 0.5f);
  }
  *(f16x8*)(Bb + (size_t)col * KS + k0) = hs;
  *(f16x8*)(Bb + MS + (size_t)col * KS + k0) = hd;
}

// ---- step GEMM: C = S·Bsum ± |S|·Bdif --------------------------------------
// R12 skeleton verbatim (BK=64, 8 waves 4Mx2N 64x64, gload_lds both operands,
// chunk^=(row&7) swizzle, 128 KiB double buffer, stage(t+1) at tile start,
// vmcnt(0) at tile end) with 32x32x16 MFMA: half the MFMA instructions,
// 15% higher matrix-pipe rate. Fragment: 8 contiguous f16 at
// [row=lane&31][ks*16+(lane>>5)*8]; chunk = ks*2+(lane>>5), same swizzle.
__global__ __launch_bounds__(512, 1) void k_gemm(
    const f16* __restrict__ A,     // [2D][KS] signed state
    const f16* __restrict__ Bb,    // [2][D][KS] Bsum,Bdif (transposed)
    f16* __restrict__ BTn,         // next layer's B buffer
    const float* __restrict__ nAl, const float* __restrict__ nAu,
    const float* __restrict__ w1, const float* __restrict__ w2,
    float* __restrict__ bdst,      // blbu (t<7) or outacc (t=7)
    f16* __restrict__ An,          // [2D][KS] next state
    const int do_tr, const int wstate) {
  __shared__ __align__(16) f16 lds[2 * BUFSZ];   // 128 KiB double buffer
  const size_t MS = (size_t)D * D;

  // bijective XCD swizzle over the 16x16 tile grid
  const int flat = blockIdx.x;
  const int xcd = flat & 7, idx = flat >> 3;
  const int by = (xcd >> 1) * 4 + (idx >> 3);
  const int bx = (xcd & 1) * 8 + (idx & 7);
  const int m0 = by * BM;
  const int n0 = bx * BN;

  const int tid = threadIdx.x;
  const int wave = tid >> 6, lane = tid & 63;
  const int wm = (wave & 3) * 64, wn = (wave >> 2) * 64;
  const int l31 = lane & 31, l5 = lane >> 5;
  const int sub = lane >> 3;                 // staging row within 8-row region
  const int cg = ((lane & 7) ^ sub) * 8;     // inverse-swizzled src chunk
  const int low = (m0 < D) ? 1 : 0;
  const unsigned amask = low ? 0x7FFF7FFFu : 0xFFFFFFFFu;  // |S| or -|S|
  const unsigned omask = low ? 0x00000000u : 0x80008000u;
  const f16* Bs = Bb;
  const f16* Bd = Bb + MS;

  f32x16 acc[2][2];
#pragma unroll
  for (int mt = 0; mt < 2; ++mt)
#pragma unroll
    for (int nt = 0; nt < 2; ++nt)
      acc[mt][nt] = (f32x16){0.f};

  // stage one K-tile: 8 gload16/thread (A: 4 regions, Bsum: 2, Bdif: 2)
  auto stage = [&](int kt, int buf) {
    f16* bA = lds + buf * BUFSZ;
    f16* bB = bA + AROWS * BK;
    const size_t gk = (size_t)kt * BK;
#pragma unroll
    for (int i = 0; i < 4; ++i) {
      const int r = i * 8 + wave;            // A regions 0..31
      gload16(A + (size_t)(m0 + r * 8 + sub) * KS + gk + cg, bA + r * 512);
    }
#pragma unroll
    for (int i = 0; i < 2; ++i) {
      const int r = i * 8 + wave;            // Bsum regions -> rows 0..127
      gload16(Bs + (size_t)(n0 + r * 8 + sub) * KS + gk + cg, bB + r * 512);
    }
#pragma unroll
    for (int i = 0; i < 2; ++i) {
      const int r = i * 8 + wave;            // Bdif regions -> rows 128..255
      gload16(Bd + (size_t)(n0 + r * 8 + sub) * KS + gk + cg,
              bB + (16 + r) * 512);
    }
  };

  // prologue: stage tile 0, drain, barrier
  stage(0, 0);
  asm volatile("s_waitcnt vmcnt(0)" ::: "memory");
  __builtin_amdgcn_sched_barrier(0);
  __builtin_amdgcn_s_barrier();
  __builtin_amdgcn_sched_barrier(0);

  float trl[8], tru[8];   // in-flight transpose column (static indexing)

  for (int t = 0; t < NT; ++t) {
    const f16* bA = lds + (t & 1) * BUFSZ;
    const f16* bB = bA + AROWS * BK;
    const int tmod = t & 7;

    if (do_tr && tmod == 4) {    // store panel loaded at t-2 (drained)
      const int p = flat * 4 + (t >> 3);
      const int col = (p & 31) * 64 + (tid & 63);
      const int k0 = (p >> 5) * 64 + (tid >> 6) * 8;
      f16x8 hs, hd;
#pragma unroll
      for (int j = 0; j < 8; ++j) {
        hs[j] = (f16)((trl[j] + tru[j]) * 0.5f);
        hd[j] = (f16)((trl[j] - tru[j]) * 0.5f);
      }
      *(f16x8*)(BTn + (size_t)col * KS + k0) = hs;
      *(f16x8*)(BTn + MS + (size_t)col * KS + k0) = hd;
    }
    if (do_tr && tmod == 2) {    // issue 16 f32 column loads for panel
      const int p = flat * 4 + (t >> 3);
      const int col = (p & 31) * 64 + (tid & 63);
      const int k0 = (p >> 5) * 64 + (tid >> 6) * 8;
#pragma unroll
      for (int j = 0; j < 8; ++j) {
        trl[j] = nAl[(size_t)(k0 + j) * D + col];
        tru[j] = nAu[(size_t)(k0 + j) * D + col];
      }
    }
    __builtin_amdgcn_sched_barrier(0);   // pin VMEM issue order

    if (t + 1 < NT) stage(t + 1, (t + 1) & 1);   // prefetch next tile

#pragma unroll
    for (int ks = 0; ks < 4; ++ks) {            // K=16 slices
      const int cidx = ks * 2 + l5;             // logical chunk (16B units)
      const int ch = (cidx ^ (lane & 7)) * 8;   // swizzled (row&7 == lane&7)
      f16x8 a[2], bs2[2], bd2[2];
#pragma unroll
      for (int mt = 0; mt < 2; ++mt)
        a[mt] = *(const f16x8*)(bA + (wm + mt * 32 + l31) * BK + ch);
#pragma unroll
      for (int nt = 0; nt < 2; ++nt) {
        bs2[nt] = *(const f16x8*)(bB + (wn + nt * 32 + l31) * BK + ch);
        bd2[nt] = *(const f16x8*)(bB + (128 + wn + nt * 32 + l31) * BK + ch);
      }
      __builtin_amdgcn_s_setprio(1);
#pragma unroll
      for (int mt = 0; mt < 2; ++mt)
#pragma unroll
        for (int nt = 0; nt < 2; ++nt)
          acc[mt][nt] = __builtin_amdgcn_mfma_f32_32x32x16_f16(
              bs2[nt], a[mt], acc[mt][nt], 0, 0, 0);
      f16x8 ax[2];
#pragma unroll
      for (int mt = 0; mt < 2; ++mt) {          // |S| (lower) or -|S| (upper)
        u32x4 u = *(const u32x4*)&a[mt];
        u = (u & amask) | omask;
        ax[mt] = *(const f16x8*)&u;
      }
#pragma unroll
      for (int mt = 0; mt < 2; ++mt)
#pragma unroll
        for (int nt = 0; nt < 2; ++nt)
          acc[mt][nt] = __builtin_amdgcn_mfma_f32_32x32x16_f16(
              bd2[nt], ax[mt], acc[mt][nt], 0, 0, 0);
      __builtin_amdgcn_s_setprio(0);
    }

    asm volatile("s_waitcnt vmcnt(0)" ::: "memory");   // next tile landed
    __builtin_amdgcn_sched_barrier(0);
    __builtin_amdgcn_s_barrier();
    __builtin_amdgcn_sched_barrier(0);
  }

  // ---- epilogue: signed state store + fused bias contribution ----
  // D layout (32x32, swapped operands): out_row = m-base + (lane&31),
  // out_col = n-base + (reg&3) + 8*(reg>>2) + 4*(lane>>5).
  f32x4 w1v[2][4], w2v[2][4];
#pragma unroll
  for (int nt = 0; nt < 2; ++nt)
#pragma unroll
    for (int rg = 0; rg < 4; ++rg) {
      const int cb = n0 + wn + nt * 32 + rg * 8 + l5 * 4;
      w1v[nt][rg] = *(const f32x4*)(w1 + cb);
      w2v[nt][rg] = *(const f32x4*)(w2 + cb);
    }
  float rowsum[2] = {0.f, 0.f};
#pragma unroll
  for (int mt = 0; mt < 2; ++mt) {
    const size_t row = (size_t)(m0 + wm + mt * 32 + l31);
#pragma unroll
    for (int nt = 0; nt < 2; ++nt) {
#pragma unroll
      for (int rg = 0; rg < 4; ++rg) {
        const int cb = n0 + wn + nt * 32 + rg * 8 + l5 * 4;
        f16x4 h;
#pragma unroll
        for (int j = 0; j < 4; ++j) {
          float v = acc[mt][nt][rg * 4 + j];
          float pf = fmaxf(v, 0.f), qf = fminf(v, 0.f);
          h[j] = (f16)v;
          float wa = low ? w1v[nt][rg][j] : w2v[nt][rg][j];
          float wb = low ? w2v[nt][rg][j] : w1v[nt][rg][j];
          rowsum[mt] += pf * wa + qf * wb;
        }
        if (wstate)
          *(f16x4*)(An + row * KS + cb) = h;
      }
    }
  }
#pragma unroll
  for (int mt = 0; mt < 2; ++mt) {
    float v = rowsum[mt];
    v += __shfl_down(v, 32);
    if (lane < 32)
      atomicAdd(bdst + m0 + wm + mt * 32 + lane, v);
  }
}

// ---- final: out[R] = outacc[R] + blbu[R] -----------------------------------
__global__ __launch_bounds__(256) void k_final(
    const float* __restrict__ outacc, const float* __restrict__ blbu,
    float* __restrict__ out) {
  const int R = blockIdx.x * 256 + threadIdx.x;
  out[R] = outacc[R] + blbu[R];
}

// ---- host ------------------------------------------------------------------
extern "C" void kernel_launch(void* const* d_in, const int* in_sizes, int n_in,
                              void* d_out, int out_size, void* d_ws, size_t ws_size,
                              hipStream_t stream) {
  (void)in_sizes; (void)n_in; (void)out_size;
  const float* A   = (const float*)d_in[0];
  const float* b   = (const float*)d_in[1];
  const float* hAl = (const float*)d_in[2];
  const float* hAu = (const float*)d_in[3];
  const float* hbl = (const float*)d_in[4];
  const float* hbu = (const float*)d_in[5];
  const float* lo  = (const float*)d_in[6];
  const float* up  = (const float*)d_in[7];
  float* out = (float*)d_out;

  const size_t AS = (size_t)2 * D * KS;     // signed state elems (f16)
  const size_t BS = (size_t)2 * D * D;      // Bsum+Bdif elems (f16)
  const size_t MS = (size_t)D * D;
  char* base = (char*)d_ws;
  f16* Ab0   = (f16*)base;
  f16* Ab1   = Ab0 + AS;
  f16* Bb0   = Ab1 + AS;
  float* blbu   = (float*)(Bb0 + BS);
  float* outacc = blbu + 2 * D;
  f16* Bb1   = (f16*)(outacc + 2 * D);
  const size_t need_fused = (size_t)((char*)(Bb1 + BS) - base);
  const bool fused = ws_size >= need_fused;

  k_init<<<dim3(D), 256, 0, stream>>>(
      A, b, hbl + (size_t)7 * D, hbu + (size_t)7 * D, Ab0, blbu, outacc);
  k_prep<<<dim3(1024), 512, 0, stream>>>(          // layer 7 -> Bb0
      hAl + (size_t)7 * MS, hAu + (size_t)7 * MS, Bb0);

  f16* cur = Ab0;
  f16* nxt = Ab1;
  for (int t = 0; t < L; ++t) {
    const int nlayer = 6 - t;   // layer for step t+1 (bias weights + transpose)
    const float* w1 = (t < 7) ? hbl + (size_t)nlayer * D : lo;
    const float* w2 = (t < 7) ? hbu + (size_t)nlayer * D : up;
    float* bd = (t < 7) ? blbu : outacc;
    f16* BT  = (fused && (t & 1)) ? Bb1 : Bb0;
    f16* BTn = fused ? ((t & 1) ? Bb0 : Bb1) : Bb0;
    const float* nl = (t < 7) ? hAl + (size_t)nlayer * MS : hAl;
    const float* nu = (t < 7) ? hAu + (size_t)nlayer * MS : hAu;
    if (!fused && t > 0)
      k_prep<<<dim3(1024), 512, 0, stream>>>(
          hAl + (size_t)(7 - t) * MS, hAu + (size_t)(7 - t) * MS, Bb0);
    const int do_tr = (fused && t < 7) ? 1 : 0;
    const int wstate = (t < 7) ? 1 : 0;
    k_gemm<<<dim3(256), 512, 0, stream>>>(cur, BT, BTn, nl, nu, w1, w2, bd,
                                          nxt, do_tr, wstate);
    f16* tmp = cur; cur = nxt; nxt = tmp;
  }
  k_final<<<dim3(2 * D / 256), 256, 0, stream>>>(outacc, blbu, out);
}

// Round 15
// 613.524 us; speedup vs baseline: 1.0729x; 1.0729x over previous
//
#include <hip/hip_runtime.h>
#include <cstdint>
#include <cstddef>

#define D 2048
#define L 8
#define KS 2048            // state/B k-extent (signed state)
#define BM 256
#define BN 128
#define BK 64
#define NT (KS / BK)       // 32 K-tiles
#define AROWS 256          // staged A rows
#define BROWS 256          // staged B rows: 128 sum + 128 dif
#define BUFSZ ((AROWS + BROWS) * BK)   // 32768 f16 = 64 KiB per buffer

typedef _Float16 f16;
typedef _Float16 f16x4 __attribute__((ext_vector_type(4)));
typedef _Float16 f16x8 __attribute__((ext_vector_type(8)));
typedef float f32x4 __attribute__((ext_vector_type(4)));
typedef unsigned int u32x4 __attribute__((ext_vector_type(4)));

__device__ __forceinline__ void gload16(const void* g, void* l) {
  __builtin_amdgcn_global_load_lds(
      (const __attribute__((address_space(1))) void*)g,
      (__attribute__((address_space(3))) void*)l, 16, 0, 0);
}

// ---- init: signed A into both chains, bias init + step-0 contribution ------
__global__ __launch_bounds__(256) void k_init(
    const float* __restrict__ A, const float* __restrict__ b,
    const float* __restrict__ db1, const float* __restrict__ db2,  // layer 7
    f16* __restrict__ Ab, float* __restrict__ blbu, float* __restrict__ outacc) {
  const int m = blockIdx.x, tid = threadIdx.x;
  if (m < 2) {
    f32x4 z = {0.f, 0.f, 0.f, 0.f};
    *(f32x4*)(outacc + m * 2048 + tid * 8) = z;
    *(f32x4*)(outacc + m * 2048 + tid * 8 + 4) = z;
  }
  const int k = tid * 8;
  size_t i = (size_t)m * D + k;
  f32x4 a0 = *(const f32x4*)(A + i);
  f32x4 a1 = *(const f32x4*)(A + i + 4);
  f16x8 h;
  float cL = 0.f, cU = 0.f;
#pragma unroll
  for (int j = 0; j < 8; ++j) {
    float v = (j < 4) ? a0[j] : a1[j - 4];
    h[j] = (f16)v;
    float pf = fmaxf(v, 0.f), nf = fminf(v, 0.f);
    float w1 = db1[k + j], w2 = db2[k + j];
    cL += pf * w1 + nf * w2;
    cU += pf * w2 + nf * w1;
  }
  *(f16x8*)(Ab + (size_t)m * KS + k) = h;
  *(f16x8*)(Ab + (size_t)(D + m) * KS + k) = h;

  __shared__ float redL[4], redU[4];
#pragma unroll
  for (int off = 32; off > 0; off >>= 1) {
    cL += __shfl_down(cL, off);
    cU += __shfl_down(cU, off);
  }
  const int wave = tid >> 6, lane = tid & 63;
  if (lane == 0) { redL[wave] = cL; redU[wave] = cU; }
  __syncthreads();
  if (tid == 0) {
    float bL = b[m] + redL[0] + redL[1] + redL[2] + redL[3];
    float bU = b[m] + redU[0] + redU[1] + redU[2] + redU[3];
    blbu[m] = bL; blbu[D + m] = bU;
  }
}

// ---- standalone prep: Bsum/Bdif transposed panels (layer 7 bootstrap) ------
__global__ __launch_bounds__(512) void k_prep(
    const float* __restrict__ srcAl, const float* __restrict__ srcAu,
    f16* __restrict__ Bb) {
  const int p = blockIdx.x, tid = threadIdx.x;
  const size_t MS = (size_t)D * D;
  const int col = (p & 31) * 64 + (tid & 63);
  const int k0 = (p >> 5) * 64 + (tid >> 6) * 8;
  float sl[8], su[8];
#pragma unroll
  for (int j = 0; j < 8; ++j) {
    sl[j] = srcAl[(size_t)(k0 + j) * D + col];
    su[j] = srcAu[(size_t)(k0 + j) * D + col];
  }
  f16x8 hs, hd;
#pragma unroll
  for (int j = 0; j < 8; ++j) {
    hs[j] = (f16)((sl[j] + su[j]) * 0.5f);
    hd[j] = (f16)((sl[j] - su[j]) * 0.5f);
  }
  *(f16x8*)(Bb + (size_t)col * KS + k0) = hs;
  *(f16x8*)(Bb + MS + (size_t)col * KS + k0) = hd;
}

// ---- step GEMM: C = S·Bsum ± |S|·Bdif --------------------------------------
// R2/R8 skeleton: BK=64, 8 waves (4M x 2N, 64x64 each), all operands staged
// via gload_lds with the measured-zero-conflict chunk^=(row&7) swizzle.
// Signed state: 64 MFMA per wave per tile (2 k-slices x (16 sum + 16 dif)).
// Double buffer (128 KiB); stage(t+1) issued at tile start -> vmcnt(0) at
// tile end has ~2500 cyc of MFMA cover. In-loop transpose rides one tile.
__global__ __launch_bounds__(512, 1) void k_gemm(
    const f16* __restrict__ A,     // [2D][KS] signed state
    const f16* __restrict__ Bb,    // [2][D][KS] Bsum,Bdif (transposed)
    f16* __restrict__ BTn,         // next layer's B buffer
    const float* __restrict__ nAl, const float* __restrict__ nAu,
    const float* __restrict__ w1, const float* __restrict__ w2,
    float* __restrict__ bdst,      // blbu (t<7) or outacc (t=7)
    f16* __restrict__ An,          // [2D][KS] next state
    const int do_tr, const int wstate) {
  __shared__ __align__(16) f16 lds[2 * BUFSZ];   // 128 KiB double buffer
  const size_t MS = (size_t)D * D;

  // bijective XCD swizzle over the 16x16 tile grid
  const int flat = blockIdx.x;
  const int xcd = flat & 7, idx = flat >> 3;
  const int by = (xcd >> 1) * 4 + (idx >> 3);
  const int bx = (xcd & 1) * 8 + (idx & 7);
  const int m0 = by * BM;
  const int n0 = bx * BN;

  const int tid = threadIdx.x;
  const int wave = tid >> 6, lane = tid & 63;
  const int wm = (wave & 3) * 64, wn = (wave >> 2) * 64;
  const int lr = lane & 15, lq = lane >> 4;
  const int sub = lane >> 3;                 // staging row within 8-row region
  const int cg = ((lane & 7) ^ sub) * 8;     // inverse-swizzled src chunk
  const int low = (m0 < D) ? 1 : 0;
  const unsigned amask = low ? 0x7FFF7FFFu : 0xFFFFFFFFu;  // |S| or -|S|
  const unsigned omask = low ? 0x00000000u : 0x80008000u;
  const f16* Bs = Bb;
  const f16* Bd = Bb + MS;

  f32x4 acc[4][4];
#pragma unroll
  for (int m = 0; m < 4; ++m)
#pragma unroll
    for (int n = 0; n < 4; ++n)
      acc[m][n] = (f32x4){0.f, 0.f, 0.f, 0.f};

  // stage one K-tile: 8 gload16/thread (A: 4 regions, Bsum: 2, Bdif: 2)
  auto stage = [&](int kt, int buf) {
    f16* bA = lds + buf * BUFSZ;
    f16* bB = bA + AROWS * BK;
    const size_t gk = (size_t)kt * BK;
#pragma unroll
    for (int i = 0; i < 4; ++i) {
      const int r = i * 8 + wave;            // A regions 0..31
      gload16(A + (size_t)(m0 + r * 8 + sub) * KS + gk + cg, bA + r * 512);
    }
#pragma unroll
    for (int i = 0; i < 2; ++i) {
      const int r = i * 8 + wave;            // Bsum regions 0..15 -> rows 0..127
      gload16(Bs + (size_t)(n0 + r * 8 + sub) * KS + gk + cg, bB + r * 512);
    }
#pragma unroll
    for (int i = 0; i < 2; ++i) {
      const int r = i * 8 + wave;            // Bdif regions -> rows 128..255
      gload16(Bd + (size_t)(n0 + r * 8 + sub) * KS + gk + cg,
              bB + (16 + r) * 512);
    }
  };

  // prologue: stage tile 0, drain, barrier
  stage(0, 0);
  asm volatile("s_waitcnt vmcnt(0)" ::: "memory");
  __builtin_amdgcn_sched_barrier(0);
  __builtin_amdgcn_s_barrier();
  __builtin_amdgcn_sched_barrier(0);

  float trl[8], tru[8];   // in-flight transpose column (static indexing)

  for (int t = 0; t < NT; ++t) {
    const f16* bA = lds + (t & 1) * BUFSZ;
    const f16* bB = bA + AROWS * BK;
    const int tmod = t & 7;

    if (do_tr && tmod == 4) {    // store panel loaded at t-2 (vmcnt(0)-drained)
      const int p = flat * 4 + (t >> 3);
      const int col = (p & 31) * 64 + (tid & 63);
      const int k0 = (p >> 5) * 64 + (tid >> 6) * 8;
      f16x8 hs, hd;
#pragma unroll
      for (int j = 0; j < 8; ++j) {
        hs[j] = (f16)((trl[j] + tru[j]) * 0.5f);
        hd[j] = (f16)((trl[j] - tru[j]) * 0.5f);
      }
      *(f16x8*)(BTn + (size_t)col * KS + k0) = hs;
      *(f16x8*)(BTn + MS + (size_t)col * KS + k0) = hd;
    }
    if (do_tr && tmod == 2) {    // issue 16 f32 column loads for panel
      const int p = flat * 4 + (t >> 3);
      const int col = (p & 31) * 64 + (tid & 63);
      const int k0 = (p >> 5) * 64 + (tid >> 6) * 8;
#pragma unroll
      for (int j = 0; j < 8; ++j) {
        trl[j] = nAl[(size_t)(k0 + j) * D + col];
        tru[j] = nAu[(size_t)(k0 + j) * D + col];
      }
    }
    __builtin_amdgcn_sched_barrier(0);   // pin VMEM issue order

    if (t + 1 < NT) stage(t + 1, (t + 1) & 1);   // prefetch next tile

#pragma unroll
    for (int ks = 0; ks < 2; ++ks) {
      f16x8 a[4], bs4[4], bd4[4];
#pragma unroll
      for (int m = 0; m < 4; ++m)
        a[m] = *(const f16x8*)(bA + (wm + m * 16 + lr) * BK
                               + ((ks * 4 + lq) ^ (lane & 7)) * 8);
#pragma unroll
      for (int n = 0; n < 4; ++n) {
        const int ch = ((ks * 4 + lq) ^ (lane & 7)) * 8;
        bs4[n] = *(const f16x8*)(bB + (wn + n * 16 + lr) * BK + ch);
        bd4[n] = *(const f16x8*)(bB + (128 + wn + n * 16 + lr) * BK + ch);
      }
      __builtin_amdgcn_s_setprio(1);
#pragma unroll
      for (int m = 0; m < 4; ++m)
#pragma unroll
        for (int n = 0; n < 4; ++n)
          acc[m][n] = __builtin_amdgcn_mfma_f32_16x16x32_f16(
              bs4[n], a[m], acc[m][n], 0, 0, 0);
      f16x8 ax[4];
#pragma unroll
      for (int m = 0; m < 4; ++m) {       // |S| (lower) or -|S| (upper)
        u32x4 u = *(const u32x4*)&a[m];
        u = (u & amask) | omask;
        ax[m] = *(const f16x8*)&u;
      }
#pragma unroll
      for (int m = 0; m < 4; ++m)
#pragma unroll
        for (int n = 0; n < 4; ++n)
          acc[m][n] = __builtin_amdgcn_mfma_f32_16x16x32_f16(
              bd4[n], ax[m], acc[m][n], 0, 0, 0);
      __builtin_amdgcn_s_setprio(0);
    }

    asm volatile("s_waitcnt vmcnt(0)" ::: "memory");   // next tile landed
    __builtin_amdgcn_sched_barrier(0);
    __builtin_amdgcn_s_barrier();
    __builtin_amdgcn_sched_barrier(0);
  }

  // ---- epilogue: signed state store + fused bias contribution ----
  f32x4 w1v[4], w2v[4];
#pragma unroll
  for (int n = 0; n < 4; ++n) {
    const int col = n0 + wn + n * 16 + lq * 4;
    w1v[n] = *(const f32x4*)(w1 + col);
    w2v[n] = *(const f32x4*)(w2 + col);
  }
  float rowsum[4] = {0.f, 0.f, 0.f, 0.f};
#pragma unroll
  for (int m = 0; m < 4; ++m) {
#pragma unroll
    for (int n = 0; n < 4; ++n) {
      const size_t row = (size_t)(m0 + wm + m * 16 + lr);
      const int col = n0 + wn + n * 16 + lq * 4;
      f16x4 h;
#pragma unroll
      for (int r = 0; r < 4; ++r) {
        float v = acc[m][n][r];
        float pf = fmaxf(v, 0.f), qf = fminf(v, 0.f);
        h[r] = (f16)v;
        float wa = low ? w1v[n][r] : w2v[n][r];
        float wb = low ? w2v[n][r] : w1v[n][r];
        rowsum[m] += pf * wa + qf * wb;
      }
      if (wstate)
        *(f16x4*)(An + row * KS + col) = h;
    }
  }
#pragma unroll
  for (int m = 0; m < 4; ++m) {
    float v = rowsum[m];
    v += __shfl_down(v, 32);
    v += __shfl_down(v, 16);
    if (lane < 16)
      atomicAdd(bdst + m0 + wm + m * 16 + lane, v);
  }
}

// ---- final: out[R] = outacc[R] + blbu[R] -----------------------------------
__global__ __launch_bounds__(256) void k_final(
    const float* __restrict__ outacc, const float* __restrict__ blbu,
    float* __restrict__ out) {
  const int R = blockIdx.x * 256 + threadIdx.x;
  out[R] = outacc[R] + blbu[R];
}

// ---- host ------------------------------------------------------------------
extern "C" void kernel_launch(void* const* d_in, const int* in_sizes, int n_in,
                              void* d_out, int out_size, void* d_ws, size_t ws_size,
                              hipStream_t stream) {
  (void)in_sizes; (void)n_in; (void)out_size;
  const float* A   = (const float*)d_in[0];
  const float* b   = (const float*)d_in[1];
  const float* hAl = (const float*)d_in[2];
  const float* hAu = (const float*)d_in[3];
  const float* hbl = (const float*)d_in[4];
  const float* hbu = (const float*)d_in[5];
  const float* lo  = (const float*)d_in[6];
  const float* up  = (const float*)d_in[7];
  float* out = (float*)d_out;

  const size_t AS = (size_t)2 * D * KS;     // signed state elems (f16)
  const size_t BS = (size_t)2 * D * D;      // Bsum+Bdif elems (f16)
  const size_t MS = (size_t)D * D;
  char* base = (char*)d_ws;
  f16* Ab0   = (f16*)base;
  f16* Ab1   = Ab0 + AS;
  f16* Bb0   = Ab1 + AS;
  float* blbu   = (float*)(Bb0 + BS);
  float* outacc = blbu + 2 * D;
  f16* Bb1   = (f16*)(outacc + 2 * D);
  const size_t need_fused = (size_t)((char*)(Bb1 + BS) - base);
  const bool fused = ws_size >= need_fused;

  k_init<<<dim3(D), 256, 0, stream>>>(
      A, b, hbl + (size_t)7 * D, hbu + (size_t)7 * D, Ab0, blbu, outacc);
  k_prep<<<dim3(1024), 512, 0, stream>>>(          // layer 7 -> Bb0
      hAl + (size_t)7 * MS, hAu + (size_t)7 * MS, Bb0);

  f16* cur = Ab0;
  f16* nxt = Ab1;
  for (int t = 0; t < L; ++t) {
    const int nlayer = 6 - t;   // layer for step t+1 (bias weights + transpose)
    const float* w1 = (t < 7) ? hbl + (size_t)nlayer * D : lo;
    const float* w2 = (t < 7) ? hbu + (size_t)nlayer * D : up;
    float* bd = (t < 7) ? blbu : outacc;
    f16* BT  = (fused && (t & 1)) ? Bb1 : Bb0;
    f16* BTn = fused ? ((t & 1) ? Bb0 : Bb1) : Bb0;
    const float* nl = (t < 7) ? hAl + (size_t)nlayer * MS : hAl;
    const float* nu = (t < 7) ? hAu + (size_t)nlayer * MS : hAu;
    if (!fused && t > 0)
      k_prep<<<dim3(1024), 512, 0, stream>>>(
          hAl + (size_t)(7 - t) * MS, hAu + (size_t)(7 - t) * MS, Bb0);
    const int do_tr = (fused && t < 7) ? 1 : 0;
    const int wstate = (t < 7) ? 1 : 0;
    k_gemm<<<dim3(256), 512, 0, stream>>>(cur, BT, BTn, nl, nu, w1, w2, bd,
                                          nxt, do_tr, wstate);
    f16* tmp = cur; cur = nxt; nxt = tmp;
  }
  k_final<<<dim3(2 * D / 256), 256, 0, stream>>>(outacc, blbu, out);
}

// Round 16
// 600.211 us; speedup vs baseline: 1.0967x; 1.0222x over previous
//
#include <hip/hip_runtime.h>
#include <cstdint>
#include <cstddef>

#define D 2048
#define L 8
#define KS 2048            // state/B k-extent (signed state)
#define BM 256
#define BN 128
#define BK 64
#define NT (KS / BK)       // 32 K-tiles
#define AROWS 256          // staged A rows
#define BROWS 256          // staged B rows: 128 sum + 128 dif
#define BUFSZ ((AROWS + BROWS) * BK)   // 32768 f16 = 64 KiB per buffer
#define BUFSZ0 ((128 + 256) * BK)      // 24576 f16 = 48 KiB (gemm0 buffer)

typedef _Float16 f16;
typedef _Float16 f16x4 __attribute__((ext_vector_type(4)));
typedef _Float16 f16x8 __attribute__((ext_vector_type(8)));
typedef float f32x4 __attribute__((ext_vector_type(4)));
typedef unsigned int u32x4 __attribute__((ext_vector_type(4)));

__device__ __forceinline__ void gload16(const void* g, void* l) {
  __builtin_amdgcn_global_load_lds(
      (const __attribute__((address_space(1))) void*)g,
      (__attribute__((address_space(3))) void*)l, 16, 0, 0);
}

// ---- init: signed A into both chains, bias init + step-0 contribution ------
__global__ __launch_bounds__(256) void k_init(
    const float* __restrict__ A, const float* __restrict__ b,
    const float* __restrict__ db1, const float* __restrict__ db2,  // layer 7
    f16* __restrict__ Ab, float* __restrict__ blbu, float* __restrict__ outacc) {
  const int m = blockIdx.x, tid = threadIdx.x;
  if (m < 2) {
    f32x4 z = {0.f, 0.f, 0.f, 0.f};
    *(f32x4*)(outacc + m * 2048 + tid * 8) = z;
    *(f32x4*)(outacc + m * 2048 + tid * 8 + 4) = z;
  }
  const int k = tid * 8;
  size_t i = (size_t)m * D + k;
  f32x4 a0 = *(const f32x4*)(A + i);
  f32x4 a1 = *(const f32x4*)(A + i + 4);
  f16x8 h;
  float cL = 0.f, cU = 0.f;
#pragma unroll
  for (int j = 0; j < 8; ++j) {
    float v = (j < 4) ? a0[j] : a1[j - 4];
    h[j] = (f16)v;
    float pf = fmaxf(v, 0.f), nf = fminf(v, 0.f);
    float w1 = db1[k + j], w2 = db2[k + j];
    cL += pf * w1 + nf * w2;
    cU += pf * w2 + nf * w1;
  }
  *(f16x8*)(Ab + (size_t)m * KS + k) = h;
  *(f16x8*)(Ab + (size_t)(D + m) * KS + k) = h;

  __shared__ float redL[4], redU[4];
#pragma unroll
  for (int off = 32; off > 0; off >>= 1) {
    cL += __shfl_down(cL, off);
    cU += __shfl_down(cU, off);
  }
  const int wave = tid >> 6, lane = tid & 63;
  if (lane == 0) { redL[wave] = cL; redU[wave] = cU; }
  __syncthreads();
  if (tid == 0) {
    float bL = b[m] + redL[0] + redL[1] + redL[2] + redL[3];
    float bU = b[m] + redU[0] + redU[1] + redU[2] + redU[3];
    blbu[m] = bL; blbu[D + m] = bU;
  }
}

// ---- standalone prep: Bsum/Bdif transposed panels (layer 7 bootstrap) ------
__global__ __launch_bounds__(512) void k_prep(
    const float* __restrict__ srcAl, const float* __restrict__ srcAu,
    f16* __restrict__ Bb) {
  const int p = blockIdx.x, tid = threadIdx.x;
  const size_t MS = (size_t)D * D;
  const int col = (p & 31) * 64 + (tid & 63);
  const int k0 = (p >> 5) * 64 + (tid >> 6) * 8;
  float sl[8], su[8];
#pragma unroll
  for (int j = 0; j < 8; ++j) {
    sl[j] = srcAl[(size_t)(k0 + j) * D + col];
    su[j] = srcAu[(size_t)(k0 + j) * D + col];
  }
  f16x8 hs, hd;
#pragma unroll
  for (int j = 0; j < 8; ++j) {
    hs[j] = (f16)((sl[j] + su[j]) * 0.5f);
    hd[j] = (f16)((sl[j] - su[j]) * 0.5f);
  }
  *(f16x8*)(Bb + (size_t)col * KS + k0) = hs;
  *(f16x8*)(Bb + MS + (size_t)col * KS + k0) = hd;
}

// ---- step-0 GEMM: P = A·Bsum, Q = |A|·Bdif computed once; C_l/u = P ± Q ----
// Both chains share state at t=0, so M halves (2048). 256 blocks of
// BM=128 x BN=128, 8 waves (2M x 4N, 64x32 each), dual accumulators.
// Same BK=64 dbuf skeleton, swizzle, in-loop transpose, fused bias.
__global__ __launch_bounds__(512, 1) void k_gemm0(
    const f16* __restrict__ A,     // [2D][KS]; rows [0,D) = A (both chains eq)
    const f16* __restrict__ Bb,    // [2][D][KS] Bsum,Bdif (transposed)
    f16* __restrict__ BTn,         // next layer's B buffer
    const float* __restrict__ nAl, const float* __restrict__ nAu,
    const float* __restrict__ w1, const float* __restrict__ w2,
    float* __restrict__ bdst,      // blbu
    f16* __restrict__ An) {        // [2D][KS] next state (both chains written)
  __shared__ __align__(16) f16 lds[2 * BUFSZ0];   // 96 KiB double buffer
  const size_t MS = (size_t)D * D;

  const int flat = blockIdx.x;
  const int xcd = flat & 7, idx = flat >> 3;
  const int by = (xcd >> 1) * 4 + (idx >> 3);   // 16x16 grid, bijective
  const int bx = (xcd & 1) * 8 + (idx & 7);
  const int m0 = by * 128;
  const int n0 = bx * 128;

  const int tid = threadIdx.x;
  const int wave = tid >> 6, lane = tid & 63;
  const int wm = (wave & 1) * 64, wn = (wave >> 1) * 32;
  const int lr = lane & 15, lq = lane >> 4;
  const int sub = lane >> 3;
  const int cg = ((lane & 7) ^ sub) * 8;
  const f16* Bs = Bb;
  const f16* Bd = Bb + MS;

  f32x4 accp[4][2], accq[4][2];
#pragma unroll
  for (int m = 0; m < 4; ++m)
#pragma unroll
    for (int n = 0; n < 2; ++n) {
      accp[m][n] = (f32x4){0.f, 0.f, 0.f, 0.f};
      accq[m][n] = (f32x4){0.f, 0.f, 0.f, 0.f};
    }

  // stage: 48 regions x 8 rows (A:0..15, Bsum:16..31, Bdif:32..47)
  auto stage = [&](int kt, int buf) {
    f16* base = lds + buf * BUFSZ0;
    const size_t gk = (size_t)kt * BK;
#pragma unroll
    for (int i = 0; i < 2; ++i) {
      const int r = i * 8 + wave;
      gload16(A + (size_t)(m0 + r * 8 + sub) * KS + gk + cg, base + r * 512);
    }
#pragma unroll
    for (int i = 0; i < 2; ++i) {
      const int r = i * 8 + wave;
      gload16(Bs + (size_t)(n0 + r * 8 + sub) * KS + gk + cg,
              base + (16 + r) * 512);
    }
#pragma unroll
    for (int i = 0; i < 2; ++i) {
      const int r = i * 8 + wave;
      gload16(Bd + (size_t)(n0 + r * 8 + sub) * KS + gk + cg,
              base + (32 + r) * 512);
    }
  };

  stage(0, 0);
  asm volatile("s_waitcnt vmcnt(0)" ::: "memory");
  __builtin_amdgcn_sched_barrier(0);
  __builtin_amdgcn_s_barrier();
  __builtin_amdgcn_sched_barrier(0);

  float trl[8], tru[8];

  for (int t = 0; t < NT; ++t) {
    const f16* bA = lds + (t & 1) * BUFSZ0;
    const f16* bB = bA + 128 * BK;
    const int tmod = t & 7;

    if (tmod == 4) {
      const int p = flat * 4 + (t >> 3);
      const int col = (p & 31) * 64 + (tid & 63);
      const int k0 = (p >> 5) * 64 + (tid >> 6) * 8;
      f16x8 hs, hd;
#pragma unroll
      for (int j = 0; j < 8; ++j) {
        hs[j] = (f16)((trl[j] + tru[j]) * 0.5f);
        hd[j] = (f16)((trl[j] - tru[j]) * 0.5f);
      }
      *(f16x8*)(BTn + (size_t)col * KS + k0) = hs;
      *(f16x8*)(BTn + MS + (size_t)col * KS + k0) = hd;
    }
    if (tmod == 2) {
      const int p = flat * 4 + (t >> 3);
      const int col = (p & 31) * 64 + (tid & 63);
      const int k0 = (p >> 5) * 64 + (tid >> 6) * 8;
#pragma unroll
      for (int j = 0; j < 8; ++j) {
        trl[j] = nAl[(size_t)(k0 + j) * D + col];
        tru[j] = nAu[(size_t)(k0 + j) * D + col];
      }
    }
    __builtin_amdgcn_sched_barrier(0);

    if (t + 1 < NT) stage(t + 1, (t + 1) & 1);

#pragma unroll
    for (int ks = 0; ks < 2; ++ks) {
      const int ch0 = ((ks * 4 + lq) ^ (lane & 7)) * 8;
      f16x8 a[4], bs2[2], bd2[2];
#pragma unroll
      for (int m = 0; m < 4; ++m)
        a[m] = *(const f16x8*)(bA + (wm + m * 16 + lr) * BK + ch0);
#pragma unroll
      for (int n = 0; n < 2; ++n) {
        bs2[n] = *(const f16x8*)(bB + (wn + n * 16 + lr) * BK + ch0);
        bd2[n] = *(const f16x8*)(bB + (128 + wn + n * 16 + lr) * BK + ch0);
      }
      __builtin_amdgcn_s_setprio(1);
#pragma unroll
      for (int m = 0; m < 4; ++m)
#pragma unroll
        for (int n = 0; n < 2; ++n)
          accp[m][n] = __builtin_amdgcn_mfma_f32_16x16x32_f16(
              bs2[n], a[m], accp[m][n], 0, 0, 0);
      f16x8 ax[4];
#pragma unroll
      for (int m = 0; m < 4; ++m) {         // |A|
        u32x4 u = *(const u32x4*)&a[m];
        u = u & 0x7FFF7FFFu;
        ax[m] = *(const f16x8*)&u;
      }
#pragma unroll
      for (int m = 0; m < 4; ++m)
#pragma unroll
        for (int n = 0; n < 2; ++n)
          accq[m][n] = __builtin_amdgcn_mfma_f32_16x16x32_f16(
              bd2[n], ax[m], accq[m][n], 0, 0, 0);
      __builtin_amdgcn_s_setprio(0);
    }

    asm volatile("s_waitcnt vmcnt(0)" ::: "memory");
    __builtin_amdgcn_sched_barrier(0);
    __builtin_amdgcn_s_barrier();
    __builtin_amdgcn_sched_barrier(0);
  }

  // ---- epilogue: C_l = P+Q, C_u = P-Q; state stores + bias for both chains
  f32x4 w1v[2], w2v[2];
#pragma unroll
  for (int n = 0; n < 2; ++n) {
    const int col = n0 + wn + n * 16 + lq * 4;
    w1v[n] = *(const f32x4*)(w1 + col);
    w2v[n] = *(const f32x4*)(w2 + col);
  }
  float rsl[4] = {0.f, 0.f, 0.f, 0.f}, rsu[4] = {0.f, 0.f, 0.f, 0.f};
#pragma unroll
  for (int m = 0; m < 4; ++m) {
#pragma unroll
    for (int n = 0; n < 2; ++n) {
      const size_t row = (size_t)(m0 + wm + m * 16 + lr);
      const int col = n0 + wn + n * 16 + lq * 4;
      f16x4 hl, hu;
#pragma unroll
      for (int r = 0; r < 4; ++r) {
        float vl = accp[m][n][r] + accq[m][n][r];
        float vu = accp[m][n][r] - accq[m][n][r];
        hl[r] = (f16)vl; hu[r] = (f16)vu;
        float plf = fmaxf(vl, 0.f), nlf = fminf(vl, 0.f);
        float puf = fmaxf(vu, 0.f), nuf = fminf(vu, 0.f);
        rsl[m] += plf * w1v[n][r] + nlf * w2v[n][r];
        rsu[m] += puf * w2v[n][r] + nuf * w1v[n][r];
      }
      *(f16x4*)(An + row * KS + col) = hl;
      *(f16x4*)(An + (D + row) * KS + col) = hu;
    }
  }
#pragma unroll
  for (int m = 0; m < 4; ++m) {
    float vl = rsl[m], vu = rsu[m];
    vl += __shfl_down(vl, 32); vl += __shfl_down(vl, 16);
    vu += __shfl_down(vu, 32); vu += __shfl_down(vu, 16);
    if (lane < 16) {
      atomicAdd(bdst + m0 + wm + m * 16 + lane, vl);
      atomicAdd(bdst + D + m0 + wm + m * 16 + lane, vu);
    }
  }
}

// ---- step GEMM: C = S·Bsum ± |S|·Bdif (R12 verbatim) -----------------------
__global__ __launch_bounds__(512, 1) void k_gemm(
    const f16* __restrict__ A,     // [2D][KS] signed state
    const f16* __restrict__ Bb,    // [2][D][KS] Bsum,Bdif (transposed)
    f16* __restrict__ BTn,         // next layer's B buffer
    const float* __restrict__ nAl, const float* __restrict__ nAu,
    const float* __restrict__ w1, const float* __restrict__ w2,
    float* __restrict__ bdst,      // blbu (t<7) or outacc (t=7)
    f16* __restrict__ An,          // [2D][KS] next state
    const int do_tr, const int wstate) {
  __shared__ __align__(16) f16 lds[2 * BUFSZ];   // 128 KiB double buffer
  const size_t MS = (size_t)D * D;

  const int flat = blockIdx.x;
  const int xcd = flat & 7, idx = flat >> 3;
  const int by = (xcd >> 1) * 4 + (idx >> 3);
  const int bx = (xcd & 1) * 8 + (idx & 7);
  const int m0 = by * BM;
  const int n0 = bx * BN;

  const int tid = threadIdx.x;
  const int wave = tid >> 6, lane = tid & 63;
  const int wm = (wave & 3) * 64, wn = (wave >> 2) * 64;
  const int lr = lane & 15, lq = lane >> 4;
  const int sub = lane >> 3;
  const int cg = ((lane & 7) ^ sub) * 8;
  const int low = (m0 < D) ? 1 : 0;
  const unsigned amask = low ? 0x7FFF7FFFu : 0xFFFFFFFFu;  // |S| or -|S|
  const unsigned omask = low ? 0x00000000u : 0x80008000u;
  const f16* Bs = Bb;
  const f16* Bd = Bb + MS;

  f32x4 acc[4][4];
#pragma unroll
  for (int m = 0; m < 4; ++m)
#pragma unroll
    for (int n = 0; n < 4; ++n)
      acc[m][n] = (f32x4){0.f, 0.f, 0.f, 0.f};

  auto stage = [&](int kt, int buf) {
    f16* bA = lds + buf * BUFSZ;
    f16* bB = bA + AROWS * BK;
    const size_t gk = (size_t)kt * BK;
#pragma unroll
    for (int i = 0; i < 4; ++i) {
      const int r = i * 8 + wave;
      gload16(A + (size_t)(m0 + r * 8 + sub) * KS + gk + cg, bA + r * 512);
    }
#pragma unroll
    for (int i = 0; i < 2; ++i) {
      const int r = i * 8 + wave;
      gload16(Bs + (size_t)(n0 + r * 8 + sub) * KS + gk + cg, bB + r * 512);
    }
#pragma unroll
    for (int i = 0; i < 2; ++i) {
      const int r = i * 8 + wave;
      gload16(Bd + (size_t)(n0 + r * 8 + sub) * KS + gk + cg,
              bB + (16 + r) * 512);
    }
  };

  stage(0, 0);
  asm volatile("s_waitcnt vmcnt(0)" ::: "memory");
  __builtin_amdgcn_sched_barrier(0);
  __builtin_amdgcn_s_barrier();
  __builtin_amdgcn_sched_barrier(0);

  float trl[8], tru[8];

  for (int t = 0; t < NT; ++t) {
    const f16* bA = lds + (t & 1) * BUFSZ;
    const f16* bB = bA + AROWS * BK;
    const int tmod = t & 7;

    if (do_tr && tmod == 4) {
      const int p = flat * 4 + (t >> 3);
      const int col = (p & 31) * 64 + (tid & 63);
      const int k0 = (p >> 5) * 64 + (tid >> 6) * 8;
      f16x8 hs, hd;
#pragma unroll
      for (int j = 0; j < 8; ++j) {
        hs[j] = (f16)((trl[j] + tru[j]) * 0.5f);
        hd[j] = (f16)((trl[j] - tru[j]) * 0.5f);
      }
      *(f16x8*)(BTn + (size_t)col * KS + k0) = hs;
      *(f16x8*)(BTn + MS + (size_t)col * KS + k0) = hd;
    }
    if (do_tr && tmod == 2) {
      const int p = flat * 4 + (t >> 3);
      const int col = (p & 31) * 64 + (tid & 63);
      const int k0 = (p >> 5) * 64 + (tid >> 6) * 8;
#pragma unroll
      for (int j = 0; j < 8; ++j) {
        trl[j] = nAl[(size_t)(k0 + j) * D + col];
        tru[j] = nAu[(size_t)(k0 + j) * D + col];
      }
    }
    __builtin_amdgcn_sched_barrier(0);

    if (t + 1 < NT) stage(t + 1, (t + 1) & 1);

#pragma unroll
    for (int ks = 0; ks < 2; ++ks) {
      f16x8 a[4], bs4[4], bd4[4];
#pragma unroll
      for (int m = 0; m < 4; ++m)
        a[m] = *(const f16x8*)(bA + (wm + m * 16 + lr) * BK
                               + ((ks * 4 + lq) ^ (lane & 7)) * 8);
#pragma unroll
      for (int n = 0; n < 4; ++n) {
        const int ch = ((ks * 4 + lq) ^ (lane & 7)) * 8;
        bs4[n] = *(const f16x8*)(bB + (wn + n * 16 + lr) * BK + ch);
        bd4[n] = *(const f16x8*)(bB + (128 + wn + n * 16 + lr) * BK + ch);
      }
      __builtin_amdgcn_s_setprio(1);
#pragma unroll
      for (int m = 0; m < 4; ++m)
#pragma unroll
        for (int n = 0; n < 4; ++n)
          acc[m][n] = __builtin_amdgcn_mfma_f32_16x16x32_f16(
              bs4[n], a[m], acc[m][n], 0, 0, 0);
      f16x8 ax[4];
#pragma unroll
      for (int m = 0; m < 4; ++m) {
        u32x4 u = *(const u32x4*)&a[m];
        u = (u & amask) | omask;
        ax[m] = *(const f16x8*)&u;
      }
#pragma unroll
      for (int m = 0; m < 4; ++m)
#pragma unroll
        for (int n = 0; n < 4; ++n)
          acc[m][n] = __builtin_amdgcn_mfma_f32_16x16x32_f16(
              bd4[n], ax[m], acc[m][n], 0, 0, 0);
      __builtin_amdgcn_s_setprio(0);
    }

    asm volatile("s_waitcnt vmcnt(0)" ::: "memory");
    __builtin_amdgcn_sched_barrier(0);
    __builtin_amdgcn_s_barrier();
    __builtin_amdgcn_sched_barrier(0);
  }

  f32x4 w1v[4], w2v[4];
#pragma unroll
  for (int n = 0; n < 4; ++n) {
    const int col = n0 + wn + n * 16 + lq * 4;
    w1v[n] = *(const f32x4*)(w1 + col);
    w2v[n] = *(const f32x4*)(w2 + col);
  }
  float rowsum[4] = {0.f, 0.f, 0.f, 0.f};
#pragma unroll
  for (int m = 0; m < 4; ++m) {
#pragma unroll
    for (int n = 0; n < 4; ++n) {
      const size_t row = (size_t)(m0 + wm + m * 16 + lr);
      const int col = n0 + wn + n * 16 + lq * 4;
      f16x4 h;
#pragma unroll
      for (int r = 0; r < 4; ++r) {
        float v = acc[m][n][r];
        float pf = fmaxf(v, 0.f), qf = fminf(v, 0.f);
        h[r] = (f16)v;
        float wa = low ? w1v[n][r] : w2v[n][r];
        float wb = low ? w2v[n][r] : w1v[n][r];
        rowsum[m] += pf * wa + qf * wb;
      }
      if (wstate)
        *(f16x4*)(An + row * KS + col) = h;
    }
  }
#pragma unroll
  for (int m = 0; m < 4; ++m) {
    float v = rowsum[m];
    v += __shfl_down(v, 32);
    v += __shfl_down(v, 16);
    if (lane < 16)
      atomicAdd(bdst + m0 + wm + m * 16 + lane, v);
  }
}

// ---- final: out[R] = outacc[R] + blbu[R] -----------------------------------
__global__ __launch_bounds__(256) void k_final(
    const float* __restrict__ outacc, const float* __restrict__ blbu,
    float* __restrict__ out) {
  const int R = blockIdx.x * 256 + threadIdx.x;
  out[R] = outacc[R] + blbu[R];
}

// ---- host ------------------------------------------------------------------
extern "C" void kernel_launch(void* const* d_in, const int* in_sizes, int n_in,
                              void* d_out, int out_size, void* d_ws, size_t ws_size,
                              hipStream_t stream) {
  (void)in_sizes; (void)n_in; (void)out_size;
  const float* A   = (const float*)d_in[0];
  const float* b   = (const float*)d_in[1];
  const float* hAl = (const float*)d_in[2];
  const float* hAu = (const float*)d_in[3];
  const float* hbl = (const float*)d_in[4];
  const float* hbu = (const float*)d_in[5];
  const float* lo  = (const float*)d_in[6];
  const float* up  = (const float*)d_in[7];
  float* out = (float*)d_out;

  const size_t AS = (size_t)2 * D * KS;     // signed state elems (f16)
  const size_t BS = (size_t)2 * D * D;      // Bsum+Bdif elems (f16)
  const size_t MS = (size_t)D * D;
  char* base = (char*)d_ws;
  f16* Ab0   = (f16*)base;
  f16* Ab1   = Ab0 + AS;
  f16* Bb0   = Ab1 + AS;
  float* blbu   = (float*)(Bb0 + BS);
  float* outacc = blbu + 2 * D;
  f16* Bb1   = (f16*)(outacc + 2 * D);
  const size_t need_fused = (size_t)((char*)(Bb1 + BS) - base);
  const bool fused = ws_size >= need_fused;

  k_init<<<dim3(D), 256, 0, stream>>>(
      A, b, hbl + (size_t)7 * D, hbu + (size_t)7 * D, Ab0, blbu, outacc);
  k_prep<<<dim3(1024), 512, 0, stream>>>(          // layer 7 -> Bb0
      hAl + (size_t)7 * MS, hAu + (size_t)7 * MS, Bb0);

  f16* cur = Ab0;
  f16* nxt = Ab1;
  for (int t = 0; t < L; ++t) {
    const int nlayer = 6 - t;   // layer for step t+1 (bias weights + transpose)
    const float* w1 = (t < 7) ? hbl + (size_t)nlayer * D : lo;
    const float* w2 = (t < 7) ? hbu + (size_t)nlayer * D : up;
    float* bd = (t < 7) ? blbu : outacc;
    f16* BT  = (fused && (t & 1)) ? Bb1 : Bb0;
    f16* BTn = fused ? ((t & 1) ? Bb0 : Bb1) : Bb0;
    const float* nl = (t < 7) ? hAl + (size_t)nlayer * MS : hAl;
    const float* nu = (t < 7) ? hAu + (size_t)nlayer * MS : hAu;
    if (!fused && t > 0)
      k_prep<<<dim3(1024), 512, 0, stream>>>(
          hAl + (size_t)(7 - t) * MS, hAu + (size_t)(7 - t) * MS, Bb0);
    if (t == 0 && fused) {
      k_gemm0<<<dim3(256), 512, 0, stream>>>(cur, BT, BTn, nl, nu, w1, w2,
                                             bd, nxt);
    } else {
      const int do_tr = (fused && t < 7) ? 1 : 0;
      const int wstate = (t < 7) ? 1 : 0;
      k_gemm<<<dim3(256), 512, 0, stream>>>(cur, BT, BTn, nl, nu, w1, w2, bd,
                                            nxt, do_tr, wstate);
    }
    f16* tmp = cur; cur = nxt; nxt = tmp;
  }
  k_final<<<dim3(2 * D / 256), 256, 0, stream>>>(outacc, blbu, out);
}